// Round 1
// baseline (1098.716 us; speedup 1.0000x reference)
//
#include <hip/hip_runtime.h>
#include <hip/hip_bf16.h>
#include <float.h>

// Problem constants
#define N_ROWS 32768          // 32 * 1024 query vectors
#define DIMS   64             // embedding dim
#define K_EMB  8192           // codebook size
#define BLK    256

// Kernel B tiling
#define ROW_TILE  512                     // rows per block (2 per thread)
#define ROW_TILES (N_ROWS / ROW_TILE)     // 64
#define KCHUNKS   8
#define KCHUNK    (K_EMB / KCHUNKS)       // 1024 embeddings per block's chunk
#define EC        128                     // embeddings per LDS stage
#define STAGES    (KCHUNK / EC)           // 8

// Workspace layout (bytes)
#define WS_NORMS 0
#define WS_ENC   (K_EMB * (int)sizeof(float))                              // 32768
#define WS_LOSS  (WS_ENC + N_ROWS * (int)sizeof(unsigned long long))       // 294912

// Output layout (float32 elements)
#define OUT_Q    0
#define OUT_LOSS (N_ROWS * DIMS)          // 2097152
#define OUT_IDX  (N_ROWS * DIMS + 1)      // 2097153

// ---------------------------------------------------------------------------
// Kernel A: ||e||^2 per embedding
// ---------------------------------------------------------------------------
__global__ void vq_norms(const float* __restrict__ emb, float* __restrict__ norms) {
    int j = blockIdx.x * blockDim.x + threadIdx.x;
    const float4* e4 = (const float4*)(emb + (size_t)j * DIMS);
    float s = 0.f;
#pragma unroll
    for (int q = 0; q < DIMS / 4; ++q) {
        float4 e = e4[q];
        s += e.x * e.x + e.y * e.y + e.z * e.z + e.w * e.w;
    }
    norms[j] = s;
}

// ---------------------------------------------------------------------------
// Kernel B: fused distance + argmin over a K-chunk, combined via atomicMin on
// packed (dist_bits << 16) | idx. dist >= 0 so float bit pattern is
// order-preserving as unsigned; ties resolve to the lowest index, matching
// jnp.argmin first-occurrence semantics.
// ---------------------------------------------------------------------------
__global__ __launch_bounds__(BLK, 2) void vq_argmin(
    const float* __restrict__ x, const float* __restrict__ emb,
    const float* __restrict__ norms, unsigned long long* __restrict__ enc) {
    __shared__ float se[EC * DIMS];   // 32 KB staged embeddings
    __shared__ float sn[EC];          // staged norms

    const int tid  = threadIdx.x;
    const int row0 = blockIdx.x * ROW_TILE + tid;
    const int row1 = row0 + BLK;

    // Load the two x rows into registers (64 floats each).
    float4 a[16], b[16];
    const float4* x0 = (const float4*)(x + (size_t)row0 * DIMS);
    const float4* x1 = (const float4*)(x + (size_t)row1 * DIMS);
    float xn0 = 0.f, xn1 = 0.f;
#pragma unroll
    for (int q = 0; q < 16; ++q) {
        a[q] = x0[q];
        b[q] = x1[q];
        xn0 += a[q].x * a[q].x + a[q].y * a[q].y + a[q].z * a[q].z + a[q].w * a[q].w;
        xn1 += b[q].x * b[q].x + b[q].y * b[q].y + b[q].z * b[q].z + b[q].w * b[q].w;
    }

    float best0 = FLT_MAX, best1 = FLT_MAX;
    int   bi0 = 0, bi1 = 0;

    const int kchunk_base = blockIdx.y * KCHUNK;

    for (int s = 0; s < STAGES; ++s) {
        const int kbase = kchunk_base + s * EC;
        // Stage EC embeddings: 2048 float4 across 256 threads (coalesced).
        const float4* src = (const float4*)(emb + (size_t)kbase * DIMS);
        float4* dst = (float4*)se;
#pragma unroll
        for (int i = 0; i < (EC * DIMS / 4) / BLK; ++i)
            dst[tid + i * BLK] = src[tid + i * BLK];
        if (tid < EC) sn[tid] = norms[kbase + tid];
        __syncthreads();

        for (int j = 0; j < EC; ++j) {
            const float4* e4 = (const float4*)(se + j * DIMS);  // broadcast reads
            float d0 = 0.f, d1 = 0.f;
#pragma unroll
            for (int q = 0; q < 16; ++q) {
                float4 e = e4[q];
                d0 += e.x * a[q].x + e.y * a[q].y + e.z * a[q].z + e.w * a[q].w;
                d1 += e.x * b[q].x + e.y * b[q].y + e.z * b[q].z + e.w * b[q].w;
            }
            float dist0 = fmaxf(xn0 + sn[j] - 2.f * d0, 0.f);
            float dist1 = fmaxf(xn1 + sn[j] - 2.f * d1, 0.f);
            if (dist0 < best0) { best0 = dist0; bi0 = kbase + j; }
            if (dist1 < best1) { best1 = dist1; bi1 = kbase + j; }
        }
        __syncthreads();
    }

    unsigned long long p0 =
        ((unsigned long long)__float_as_uint(best0) << 16) | (unsigned long long)bi0;
    unsigned long long p1 =
        ((unsigned long long)__float_as_uint(best1) << 16) | (unsigned long long)bi1;
    atomicMin(&enc[row0], p0);
    atomicMin(&enc[row1], p1);
}

// ---------------------------------------------------------------------------
// Kernel C: gather quantized rows, accumulate squared error, emit indices.
// ---------------------------------------------------------------------------
__global__ void vq_gather(const float* __restrict__ x, const float* __restrict__ emb,
                          const unsigned long long* __restrict__ enc,
                          float* __restrict__ out, double* __restrict__ loss_acc) {
    int row = blockIdx.x * blockDim.x + threadIdx.x;
    unsigned long long e = enc[row];
    int idx = (int)(e & 0xFFFFULL);
    const float4* ev = (const float4*)(emb + (size_t)idx * DIMS);
    const float4* xv = (const float4*)(x + (size_t)row * DIMS);
    float4* ov = (float4*)(out + (size_t)row * DIMS);
    float s = 0.f;
#pragma unroll
    for (int q = 0; q < 16; ++q) {
        float4 ee = ev[q];
        float4 xx = xv[q];
        float dx = ee.x - xx.x, dy = ee.y - xx.y, dz = ee.z - xx.z, dw = ee.w - xx.w;
        s += dx * dx + dy * dy + dz * dz + dw * dw;
        ov[q] = ee;
    }
    // wave-64 reduction
#pragma unroll
    for (int off = 32; off > 0; off >>= 1) s += __shfl_down(s, off, 64);
    if ((threadIdx.x & 63) == 0) atomicAdd(loss_acc, (double)s);
    out[OUT_IDX + row] = (float)idx;  // harness reads index chunk as float32
}

// ---------------------------------------------------------------------------
// Kernel D: finalize scalar loss = (1 + 0.25) * mean((q - x)^2)
// ---------------------------------------------------------------------------
__global__ void vq_loss(const double* __restrict__ acc, float* __restrict__ out) {
    out[OUT_LOSS] = (float)(1.25 * (*acc) / (double)(N_ROWS * DIMS));
}

// ---------------------------------------------------------------------------
extern "C" void kernel_launch(void* const* d_in, const int* in_sizes, int n_in,
                              void* d_out, int out_size, void* d_ws, size_t ws_size,
                              hipStream_t stream) {
    const float* x   = (const float*)d_in[0];
    const float* emb = (const float*)d_in[1];
    float* out = (float*)d_out;
    char*  ws  = (char*)d_ws;

    float* norms = (float*)(ws + WS_NORMS);
    unsigned long long* enc = (unsigned long long*)(ws + WS_ENC);
    double* loss_acc = (double*)(ws + WS_LOSS);

    // enc -> 0xFF.. (max), loss accumulator -> 0
    hipMemsetAsync(enc, 0xFF, N_ROWS * sizeof(unsigned long long), stream);
    hipMemsetAsync(loss_acc, 0, sizeof(double), stream);

    vq_norms<<<K_EMB / BLK, BLK, 0, stream>>>(emb, norms);
    vq_argmin<<<dim3(ROW_TILES, KCHUNKS), BLK, 0, stream>>>(x, emb, norms, enc);
    vq_gather<<<N_ROWS / BLK, BLK, 0, stream>>>(x, emb, enc, out, loss_acc);
    vq_loss<<<1, 1, 0, stream>>>(loss_acc, out);
}

// Round 3
// 552.125 us; speedup vs baseline: 1.9900x; 1.9900x over previous
//
#include <hip/hip_runtime.h>
#include <hip/hip_bf16.h>
#include <float.h>

// Problem constants
#define N_ROWS 32768          // 32 * 1024 query vectors
#define DIMS   64
#define K_EMB  8192
#define NT     (K_EMB / 16)   // 512 column tiles of 16
#define GAP_THR 0.02f         // flag threshold in f-units (f = x.e - |e|^2/2)

typedef __attribute__((ext_vector_type(8))) short s8v;   // 8 bf16 (A/B frag)
typedef __attribute__((ext_vector_type(4))) float f4v;   // C/D frag
typedef __attribute__((ext_vector_type(4))) int   i4v;   // 16B load unit

// Workspace layout (bytes)
#define WS_EFRAG 0                                   // 512 tiles * 4 frags * 64 lanes * 16B = 2 MiB
#define WS_EN2   (2 * 1024 * 1024)                   // 8192 floats: -0.5*||e||^2
#define WS_IDX   (WS_EN2 + K_EMB * 4)                // 32768 int32
#define WS_GAP   (WS_IDX + N_ROWS * 4)               // 32768 float
#define WS_LOSS  (WS_GAP + N_ROWS * 4)               // double

// Output layout (float32 elements): [quantized | loss | indices]
#define OUT_LOSS (N_ROWS * DIMS)
#define OUT_IDX  (N_ROWS * DIMS + 1)

__device__ inline short bfh(float v) {
    __hip_bfloat16 h = __float2bfloat16(v);
    return __builtin_bit_cast(short, h);
}
__device__ inline float bff(short s) {
    __hip_bfloat16 h = __builtin_bit_cast(__hip_bfloat16, s);
    return __bfloat162float(h);
}

// ---------------------------------------------------------------------------
// Prep: shuffle embeddings into MFMA B-fragment layout (hi/lo bf16 split).
// B-frag for mfma_f32_16x16x32_bf16: lane holds B[k = (lane>>4)*8 + j][n = lane&15],
// i.e. e[col0 + (lane&15)][quad*8 + j]. Frags: 0=hi k[0,32), 1=hi k[32,64),
// 2=lo k[0,32), 3=lo k[32,64). Storage: [tile][frag][lane][8 bf16] (16B/lane).
// ---------------------------------------------------------------------------
__global__ void vq_prep_e(const float* __restrict__ emb, short* __restrict__ efrag) {
    int gid = blockIdx.x * 256 + threadIdx.x;   // NT*64 = 32768 threads total
    int t = gid >> 6, lane = gid & 63;
    int m = lane & 15, q = lane >> 4;
    const float* er = emb + (size_t)(t * 16 + m) * DIMS;
    s8v hi0, lo0, hi1, lo1;
#pragma unroll
    for (int j = 0; j < 8; ++j) {
        float v0 = er[q * 8 + j];
        float v1 = er[32 + q * 8 + j];
        short h0 = bfh(v0); lo0[j] = bfh(v0 - bff(h0)); hi0[j] = h0;
        short h1 = bfh(v1); lo1[j] = bfh(v1 - bff(h1)); hi1[j] = h1;
    }
    s8v* base = (s8v*)efrag + (size_t)t * 4 * 64;
    base[0 * 64 + lane] = hi0;
    base[1 * 64 + lane] = hi1;
    base[2 * 64 + lane] = lo0;
    base[3 * 64 + lane] = lo1;
}

// -0.5 * ||e||^2 per embedding (fp32)
__global__ void vq_en2(const float* __restrict__ emb, float* __restrict__ en2) {
    int c = blockIdx.x * 256 + threadIdx.x;
    const float4* e4 = (const float4*)(emb + (size_t)c * DIMS);
    float s = 0.f;
#pragma unroll
    for (int qq = 0; qq < 16; ++qq) {
        float4 e = e4[qq];
        s += e.x * e.x + e.y * e.y + e.z * e.z + e.w * e.w;
    }
    en2[c] = -0.5f * s;
}

// ---------------------------------------------------------------------------
// Phase 1: fused split-bf16 MFMA distance + argmax(f) + second-best tracking.
// Block = 4 waves * 16 rows = 64 rows; each wave sweeps all 512 col tiles.
// ---------------------------------------------------------------------------
__global__ __launch_bounds__(256) void vq_phase1(
    const float* __restrict__ x, const short* __restrict__ efrag,
    const float* __restrict__ en2, int* __restrict__ idx_buf,
    float* __restrict__ gap_buf) {
    int tid = threadIdx.x, wid = tid >> 6, lane = tid & 63;
    int m = lane & 15, q = lane >> 4;
    int row0 = blockIdx.x * 64 + wid * 16;

    // A-frags: A[m=lane&15][k=quad*8+j], split hi/lo, two K-halves.
    const float* xr = x + (size_t)(row0 + m) * DIMS + q * 8;
    s8v ahi0, alo0, ahi1, alo1;
#pragma unroll
    for (int j = 0; j < 8; ++j) {
        float v0 = xr[j], v1 = xr[32 + j];
        short h0 = bfh(v0); alo0[j] = bfh(v0 - bff(h0)); ahi0[j] = h0;
        short h1 = bfh(v1); alo1[j] = bfh(v1 - bff(h1)); ahi1[j] = h1;
    }

    float best[4], sec[4];
    int bc[4];
#pragma unroll
    for (int r = 0; r < 4; ++r) { best[r] = -FLT_MAX; sec[r] = -FLT_MAX; bc[r] = 0; }

    const i4v* bp = (const i4v*)efrag;
#pragma unroll 2
    for (int t = 0; t < NT; ++t) {
        i4v b0 = bp[(t * 4 + 0) * 64 + lane];
        i4v b1 = bp[(t * 4 + 1) * 64 + lane];
        i4v b2 = bp[(t * 4 + 2) * 64 + lane];
        i4v b3 = bp[(t * 4 + 3) * 64 + lane];
        float c0 = en2[t * 16 + m];
        f4v acc = {c0, c0, c0, c0};   // C init = -||e_col||^2 / 2
        acc = __builtin_amdgcn_mfma_f32_16x16x32_bf16(ahi0, __builtin_bit_cast(s8v, b0), acc, 0, 0, 0);
        acc = __builtin_amdgcn_mfma_f32_16x16x32_bf16(ahi1, __builtin_bit_cast(s8v, b1), acc, 0, 0, 0);
        acc = __builtin_amdgcn_mfma_f32_16x16x32_bf16(ahi0, __builtin_bit_cast(s8v, b2), acc, 0, 0, 0);
        acc = __builtin_amdgcn_mfma_f32_16x16x32_bf16(ahi1, __builtin_bit_cast(s8v, b3), acc, 0, 0, 0);
        acc = __builtin_amdgcn_mfma_f32_16x16x32_bf16(alo0, __builtin_bit_cast(s8v, b0), acc, 0, 0, 0);
        acc = __builtin_amdgcn_mfma_f32_16x16x32_bf16(alo1, __builtin_bit_cast(s8v, b1), acc, 0, 0, 0);
        int cidx = t * 16 + m;
#pragma unroll
        for (int r = 0; r < 4; ++r) {   // C/D: col=lane&15, row=quad*4+r
            float v = acc[r];
            bool gt = v > best[r];
            sec[r]  = gt ? best[r] : fmaxf(sec[r], v);
            bc[r]   = gt ? cidx : bc[r];
            best[r] = gt ? v : best[r];
        }
    }

    // Reduce (best, bestc, second) across the 16 col-lanes of each quad.
#pragma unroll
    for (int r = 0; r < 4; ++r) {
        float b = best[r], s = sec[r];
        int c = bc[r];
#pragma unroll
        for (int off = 1; off < 16; off <<= 1) {
            float ob = __shfl_xor(b, off, 64);
            float os = __shfl_xor(s, off, 64);
            int   oc = __shfl_xor(c, off, 64);
            float nb = fmaxf(b, ob);
            float ns = fmaxf(fminf(b, ob), fmaxf(s, os));
            bool take = (ob > b) || (ob == b && oc < c);  // tie -> lowest index
            c = take ? oc : c;
            b = nb; s = ns;
        }
        if (m == 0) {
            int row = row0 + q * 4 + r;
            idx_buf[row] = c;
            gap_buf[row] = b - s;
        }
    }
}

// ---------------------------------------------------------------------------
// Phase 2: exact fp32 rescan for rows whose winning margin is below threshold.
// ---------------------------------------------------------------------------
#define FIX_ROWS 8
__global__ __launch_bounds__(256) void vq_fixup(
    const float* __restrict__ x, const float* __restrict__ emb,
    const float* __restrict__ en2, int* __restrict__ idx_buf,
    const float* __restrict__ gap_buf) {
    __shared__ float4 sx[16];
    __shared__ float sf[256];
    __shared__ int sc[256];
    int tid = threadIdx.x;
    int base = blockIdx.x * FIX_ROWS;
    for (int rr = 0; rr < FIX_ROWS; ++rr) {
        int row = base + rr;
        if (gap_buf[row] >= GAP_THR) continue;  // block-uniform branch
        if (tid < 16) sx[tid] = ((const float4*)(x + (size_t)row * DIMS))[tid];
        __syncthreads();
        float bf_ = -FLT_MAX;
        int bc_ = 0;
        for (int c = tid; c < K_EMB; c += 256) {
            const float4* er = (const float4*)(emb + (size_t)c * DIMS);
            float d = 0.f;
#pragma unroll
            for (int qq = 0; qq < 16; ++qq) {
                float4 e = er[qq];
                float4 xx = sx[qq];
                d += e.x * xx.x + e.y * xx.y + e.z * xx.z + e.w * xx.w;
            }
            float f = d + en2[c];
            if (f > bf_) { bf_ = f; bc_ = c; }
        }
        sf[tid] = bf_; sc[tid] = bc_;
        __syncthreads();
        if (tid == 0) {
            float b = sf[0]; int c = sc[0];
            for (int i = 1; i < 256; ++i)
                if (sf[i] > b || (sf[i] == b && sc[i] < c)) { b = sf[i]; c = sc[i]; }
            idx_buf[row] = c;
        }
        __syncthreads();
    }
}

// ---------------------------------------------------------------------------
// Gather quantized rows, accumulate squared error, emit indices as floats.
// ---------------------------------------------------------------------------
__global__ void vq_gather(const float* __restrict__ x, const float* __restrict__ emb,
                          const int* __restrict__ idx_buf,
                          float* __restrict__ out, double* __restrict__ loss_acc) {
    int row = blockIdx.x * blockDim.x + threadIdx.x;
    int idx = idx_buf[row];
    const float4* ev = (const float4*)(emb + (size_t)idx * DIMS);
    const float4* xv = (const float4*)(x + (size_t)row * DIMS);
    float4* ov = (float4*)(out + (size_t)row * DIMS);
    float s = 0.f;
#pragma unroll
    for (int qq = 0; qq < 16; ++qq) {
        float4 ee = ev[qq];
        float4 xx = xv[qq];
        float dx = ee.x - xx.x, dy = ee.y - xx.y, dz = ee.z - xx.z, dw = ee.w - xx.w;
        s += dx * dx + dy * dy + dz * dz + dw * dw;
        ov[qq] = ee;
    }
#pragma unroll
    for (int off = 32; off > 0; off >>= 1) s += __shfl_down(s, off, 64);
    if ((threadIdx.x & 63) == 0) atomicAdd(loss_acc, (double)s);
    out[OUT_IDX + row] = (float)idx;
}

__global__ void vq_loss(const double* __restrict__ acc, float* __restrict__ out) {
    out[OUT_LOSS] = (float)(1.25 * (*acc) / (double)(N_ROWS * DIMS));
}

// ---------------------------------------------------------------------------
extern "C" void kernel_launch(void* const* d_in, const int* in_sizes, int n_in,
                              void* d_out, int out_size, void* d_ws, size_t ws_size,
                              hipStream_t stream) {
    const float* x   = (const float*)d_in[0];
    const float* emb = (const float*)d_in[1];
    float* out = (float*)d_out;
    char*  ws  = (char*)d_ws;

    short* efrag   = (short*)(ws + WS_EFRAG);
    float* en2     = (float*)(ws + WS_EN2);
    int*   idx_buf = (int*)(ws + WS_IDX);
    float* gap_buf = (float*)(ws + WS_GAP);
    double* loss_acc = (double*)(ws + WS_LOSS);

    hipMemsetAsync(loss_acc, 0, sizeof(double), stream);

    // BUGFIX (round 2): vq_prep_e needs NT*64 = 32768 threads (128 blocks);
    // previous launch used 32 blocks, leaving 3/4 of efrag poisoned.
    vq_prep_e<<<(NT * 64) / 256, 256, 0, stream>>>(emb, efrag);         // 128 blocks
    vq_en2<<<K_EMB / 256, 256, 0, stream>>>(emb, en2);                  // 32 blocks
    vq_phase1<<<N_ROWS / 64, 256, 0, stream>>>(x, efrag, en2, idx_buf, gap_buf);  // 512 blocks
    vq_fixup<<<N_ROWS / FIX_ROWS, 256, 0, stream>>>(x, emb, en2, idx_buf, gap_buf);
    vq_gather<<<N_ROWS / 256, 256, 0, stream>>>(x, emb, idx_buf, out, loss_acc);
    vq_loss<<<1, 1, 0, stream>>>(loss_acc, out);
}

// Round 4
// 325.460 us; speedup vs baseline: 3.3759x; 1.6964x over previous
//
#include <hip/hip_runtime.h>
#include <hip/hip_bf16.h>
#include <float.h>

// Problem constants
#define N_ROWS 32768          // 32 * 1024 query vectors
#define DIMS   64
#define K_EMB  8192
#define NT     (K_EMB / 16)   // 512 column tiles of 16
// 3-term split-bf16 worst-case f-error ~6.5e-4; 1.5e-3 gives >2x margin.
#define GAP_THR 1.5e-3f

typedef __attribute__((ext_vector_type(8))) short s8v;   // 8 bf16 (A/B frag)
typedef __attribute__((ext_vector_type(4))) float f4v;   // C/D frag
typedef __attribute__((ext_vector_type(4))) int   i4v;   // 16B load unit

// Workspace layout (bytes)
#define WS_EFRAG 0                                  // 512 tiles * 4 frags * 64 lanes * 16B = 2 MiB
#define WS_EN2   (2 * 1024 * 1024)                  // 8192 floats: -0.5*||e||^2
#define WS_IDX   (WS_EN2 + K_EMB * 4)               // 32768 int32
#define WS_CTL   (WS_IDX + N_ROWS * 4)              // 16 B: {double loss; int wl_count; pad}
#define WS_WL    (WS_CTL + 16)                      // worklist, up to N_ROWS int32

// Output layout (float32 elements): [quantized | loss | indices]
#define OUT_LOSS (N_ROWS * DIMS)
#define OUT_IDX  (N_ROWS * DIMS + 1)

__device__ inline short bfh(float v) {
    __hip_bfloat16 h = __float2bfloat16(v);
    return __builtin_bit_cast(short, h);
}
__device__ inline float bff(short s) {
    __hip_bfloat16 h = __builtin_bit_cast(__hip_bfloat16, s);
    return __bfloat162float(h);
}

// ---------------------------------------------------------------------------
// Prep: shuffle embeddings into MFMA B-fragment layout (hi/lo bf16 split).
// B-frag: lane holds B[k=(lane>>4)*8+j][n=lane&15]. Frags: 0=hi k[0,32),
// 1=hi k[32,64), 2=lo k[0,32), 3=lo k[32,64). [tile][frag][lane][8 bf16].
// ---------------------------------------------------------------------------
__global__ void vq_prep_e(const float* __restrict__ emb, short* __restrict__ efrag) {
    int gid = blockIdx.x * 256 + threadIdx.x;   // NT*64 = 32768 threads total
    int t = gid >> 6, lane = gid & 63;
    int m = lane & 15, q = lane >> 4;
    const float* er = emb + (size_t)(t * 16 + m) * DIMS;
    s8v hi0, lo0, hi1, lo1;
#pragma unroll
    for (int j = 0; j < 8; ++j) {
        float v0 = er[q * 8 + j];
        float v1 = er[32 + q * 8 + j];
        short h0 = bfh(v0); lo0[j] = bfh(v0 - bff(h0)); hi0[j] = h0;
        short h1 = bfh(v1); lo1[j] = bfh(v1 - bff(h1)); hi1[j] = h1;
    }
    s8v* base = (s8v*)efrag + (size_t)t * 4 * 64;
    base[0 * 64 + lane] = hi0;
    base[1 * 64 + lane] = hi1;
    base[2 * 64 + lane] = lo0;
    base[3 * 64 + lane] = lo1;
}

// -0.5 * ||e||^2 per embedding (fp32)
__global__ void vq_en2(const float* __restrict__ emb, float* __restrict__ en2) {
    int c = blockIdx.x * 256 + threadIdx.x;
    const float4* e4 = (const float4*)(emb + (size_t)c * DIMS);
    float s = 0.f;
#pragma unroll
    for (int qq = 0; qq < 16; ++qq) {
        float4 e = e4[qq];
        s += e.x * e.x + e.y * e.y + e.z * e.z + e.w * e.w;
    }
    en2[c] = -0.5f * s;
}

// ---------------------------------------------------------------------------
// Phase 1: split-bf16 MFMA distance + argmax(f) + second-best tracking.
// 32 rows/wave (2 row-groups sharing each B load), 4 waves/block -> 128
// rows/block, 256 blocks (1/CU). 12 MFMAs/tile in 4 independent 3-chains.
// Flagged rows (gap < GAP_THR) go to a compacted worklist.
// ---------------------------------------------------------------------------
__global__ __launch_bounds__(256) void vq_phase1(
    const float* __restrict__ x, const short* __restrict__ efrag,
    const float* __restrict__ en2, int* __restrict__ idx_buf,
    int* __restrict__ wl, int* __restrict__ wl_count) {
    int tid = threadIdx.x, wid = tid >> 6, lane = tid & 63;
    int m = lane & 15, q = lane >> 4;
    int row0 = blockIdx.x * 128 + wid * 32;

    // A-frags for 2 row-groups: A[m=lane&15][k=quad*8+j], hi/lo, two K-halves.
    s8v ahi[2][2], alo[2][2];
#pragma unroll
    for (int g = 0; g < 2; ++g) {
        const float* xr = x + (size_t)(row0 + g * 16 + m) * DIMS + q * 8;
#pragma unroll
        for (int j = 0; j < 8; ++j) {
            float v0 = xr[j], v1 = xr[32 + j];
            short h0 = bfh(v0); alo[g][0][j] = bfh(v0 - bff(h0)); ahi[g][0][j] = h0;
            short h1 = bfh(v1); alo[g][1][j] = bfh(v1 - bff(h1)); ahi[g][1][j] = h1;
        }
    }

    float best[2][4], sec[2][4];
    int bc[2][4];
#pragma unroll
    for (int g = 0; g < 2; ++g)
#pragma unroll
        for (int r = 0; r < 4; ++r) { best[g][r] = -FLT_MAX; sec[g][r] = -FLT_MAX; bc[g][r] = 0; }

    const i4v* bp = (const i4v*)efrag + lane;
    // prefetch tile 0
    i4v nb0 = bp[0], nb1 = bp[64], nb2 = bp[128], nb3 = bp[192];

    for (int t = 0; t < NT; ++t) {
        i4v b0 = nb0, b1 = nb1, b2 = nb2, b3 = nb3;
        int tn = (t + 1 < NT) ? (t + 1) : t;
        const i4v* nbp = bp + (size_t)tn * 256;
        nb0 = nbp[0]; nb1 = nbp[64]; nb2 = nbp[128]; nb3 = nbp[192];
        float c0 = en2[t * 16 + m];
        int cidx = t * 16 + m;
#pragma unroll
        for (int g = 0; g < 2; ++g) {
            f4v aA = {c0, c0, c0, c0};   // C init = -||e_col||^2 / 2
            f4v aB = {0.f, 0.f, 0.f, 0.f};
            aA = __builtin_amdgcn_mfma_f32_16x16x32_bf16(ahi[g][0], __builtin_bit_cast(s8v, b0), aA, 0, 0, 0);
            aB = __builtin_amdgcn_mfma_f32_16x16x32_bf16(ahi[g][1], __builtin_bit_cast(s8v, b3), aB, 0, 0, 0);
            aA = __builtin_amdgcn_mfma_f32_16x16x32_bf16(ahi[g][1], __builtin_bit_cast(s8v, b1), aA, 0, 0, 0);
            aB = __builtin_amdgcn_mfma_f32_16x16x32_bf16(alo[g][0], __builtin_bit_cast(s8v, b0), aB, 0, 0, 0);
            aA = __builtin_amdgcn_mfma_f32_16x16x32_bf16(ahi[g][0], __builtin_bit_cast(s8v, b2), aA, 0, 0, 0);
            aB = __builtin_amdgcn_mfma_f32_16x16x32_bf16(alo[g][1], __builtin_bit_cast(s8v, b1), aB, 0, 0, 0);
#pragma unroll
            for (int r = 0; r < 4; ++r) {   // C/D: col=lane&15, row=quad*4+r
                float v = aA[r] + aB[r];
                bool gt = v > best[g][r];
                float lo2 = fminf(v, best[g][r]);
                sec[g][r]  = fmaxf(sec[g][r], lo2);
                best[g][r] = fmaxf(best[g][r], v);
                bc[g][r]   = gt ? cidx : bc[g][r];
            }
        }
    }

    // Reduce (best, idx, second) across the 16 col-lanes of each quad.
#pragma unroll
    for (int g = 0; g < 2; ++g)
#pragma unroll
    for (int r = 0; r < 4; ++r) {
        float b = best[g][r], s = sec[g][r];
        int c = bc[g][r];
#pragma unroll
        for (int off = 1; off < 16; off <<= 1) {
            float ob = __shfl_xor(b, off, 64);
            float os = __shfl_xor(s, off, 64);
            int   oc = __shfl_xor(c, off, 64);
            float nb = fmaxf(b, ob);
            float ns = fmaxf(fminf(b, ob), fmaxf(s, os));
            bool take = (ob > b) || (ob == b && oc < c);  // tie -> lowest index
            c = take ? oc : c;
            b = nb; s = ns;
        }
        if (m == 0) {
            int row = row0 + g * 16 + q * 4 + r;
            idx_buf[row] = c;
            if (b - s < GAP_THR) {
                int pos = atomicAdd(wl_count, 1);
                wl[pos] = row;
            }
        }
    }
}

// ---------------------------------------------------------------------------
// Phase 2: exact fp32 rescan of worklisted rows. One block per row,
// grid-strided; shuffle + LDS reduction.
// ---------------------------------------------------------------------------
__global__ __launch_bounds__(256) void vq_fixup2(
    const float* __restrict__ x, const float* __restrict__ emb,
    const float* __restrict__ en2, int* __restrict__ idx_buf,
    const int* __restrict__ wl, const int* __restrict__ wl_count) {
    __shared__ float4 sx[16];
    __shared__ float sbf[4];
    __shared__ int   sbc[4];
    int tid = threadIdx.x, wid = tid >> 6, lane = tid & 63;
    int cnt = *wl_count;
    for (int w = blockIdx.x; w < cnt; w += gridDim.x) {
        int row = wl[w];
        if (tid < 16) sx[tid] = ((const float4*)(x + (size_t)row * DIMS))[tid];
        __syncthreads();
        float bf_ = -FLT_MAX;
        int bc_ = 0;
        for (int c = tid; c < K_EMB; c += 256) {
            const float4* er = (const float4*)(emb + (size_t)c * DIMS);
            float d = 0.f;
#pragma unroll
            for (int qq = 0; qq < 16; ++qq) {
                float4 e = er[qq];
                float4 xx = sx[qq];
                d += e.x * xx.x + e.y * xx.y + e.z * xx.z + e.w * xx.w;
            }
            float f = d + en2[c];
            if (f > bf_) { bf_ = f; bc_ = c; }   // ascending c -> first occurrence
        }
#pragma unroll
        for (int off = 1; off < 64; off <<= 1) {
            float of = __shfl_xor(bf_, off, 64);
            int   oc = __shfl_xor(bc_, off, 64);
            if (of > bf_ || (of == bf_ && oc < bc_)) { bf_ = of; bc_ = oc; }
        }
        if (lane == 0) { sbf[wid] = bf_; sbc[wid] = bc_; }
        __syncthreads();
        if (tid == 0) {
            float b = sbf[0]; int c = sbc[0];
#pragma unroll
            for (int i = 1; i < 4; ++i)
                if (sbf[i] > b || (sbf[i] == b && sbc[i] < c)) { b = sbf[i]; c = sbc[i]; }
            idx_buf[row] = c;
        }
        __syncthreads();
    }
}

// ---------------------------------------------------------------------------
// Gather quantized rows, accumulate squared error, emit indices as floats.
// ---------------------------------------------------------------------------
__global__ void vq_gather(const float* __restrict__ x, const float* __restrict__ emb,
                          const int* __restrict__ idx_buf,
                          float* __restrict__ out, double* __restrict__ loss_acc) {
    int row = blockIdx.x * blockDim.x + threadIdx.x;
    int idx = idx_buf[row];
    const float4* ev = (const float4*)(emb + (size_t)idx * DIMS);
    const float4* xv = (const float4*)(x + (size_t)row * DIMS);
    float4* ov = (float4*)(out + (size_t)row * DIMS);
    float s = 0.f;
#pragma unroll
    for (int qq = 0; qq < 16; ++qq) {
        float4 ee = ev[qq];
        float4 xx = xv[qq];
        float dx = ee.x - xx.x, dy = ee.y - xx.y, dz = ee.z - xx.z, dw = ee.w - xx.w;
        s += dx * dx + dy * dy + dz * dz + dw * dw;
        ov[qq] = ee;
    }
#pragma unroll
    for (int off = 32; off > 0; off >>= 1) s += __shfl_down(s, off, 64);
    if ((threadIdx.x & 63) == 0) atomicAdd(loss_acc, (double)s);
    out[OUT_IDX + row] = (float)idx;
}

__global__ void vq_loss(const double* __restrict__ acc, float* __restrict__ out) {
    out[OUT_LOSS] = (float)(1.25 * (*acc) / (double)(N_ROWS * DIMS));
}

// ---------------------------------------------------------------------------
extern "C" void kernel_launch(void* const* d_in, const int* in_sizes, int n_in,
                              void* d_out, int out_size, void* d_ws, size_t ws_size,
                              hipStream_t stream) {
    const float* x   = (const float*)d_in[0];
    const float* emb = (const float*)d_in[1];
    float* out = (float*)d_out;
    char*  ws  = (char*)d_ws;

    short* efrag   = (short*)(ws + WS_EFRAG);
    float* en2     = (float*)(ws + WS_EN2);
    int*   idx_buf = (int*)(ws + WS_IDX);
    double* loss_acc = (double*)(ws + WS_CTL);
    int*   wl_count  = (int*)(ws + WS_CTL + 8);
    int*   wl        = (int*)(ws + WS_WL);

    // zero {loss_acc, wl_count} in one shot
    hipMemsetAsync(ws + WS_CTL, 0, 16, stream);

    vq_prep_e<<<(NT * 64) / 256, 256, 0, stream>>>(emb, efrag);          // 128 blocks
    vq_en2<<<K_EMB / 256, 256, 0, stream>>>(emb, en2);                   // 32 blocks
    vq_phase1<<<N_ROWS / 128, 256, 0, stream>>>(x, efrag, en2, idx_buf, wl, wl_count);  // 256 blocks
    vq_fixup2<<<512, 256, 0, stream>>>(x, emb, en2, idx_buf, wl, wl_count);
    vq_gather<<<N_ROWS / 256, 256, 0, stream>>>(x, emb, idx_buf, out, loss_acc);
    vq_loss<<<1, 1, 0, stream>>>(loss_acc, out);
}

// Round 5
// 200.681 us; speedup vs baseline: 5.4749x; 1.6218x over previous
//
#include <hip/hip_runtime.h>
#include <hip/hip_bf16.h>
#include <float.h>

// Problem constants
#define N_ROWS 32768          // 32 * 1024 query vectors
#define DIMS   64
#define K_EMB  8192
#define NT     (K_EMB / 16)   // 512 column tiles of 16
#define NTH    (NT / 2)       // 256 tiles per K-half
#define TSTAGE 8              // tiles staged per barrier round (32 KB)
#define NSTAGE (NTH / TSTAGE) // 32
// 3-term split-bf16 worst-case f-error ~6.5e-4; 1.5e-3 gives >2x margin.
#define GAP_THR 1.5e-3f

typedef __attribute__((ext_vector_type(8))) short s8v;   // 8 bf16 (A/B frag)
typedef __attribute__((ext_vector_type(4))) float f4v;   // C/D frag
typedef __attribute__((ext_vector_type(4))) int   i4v;   // 16B load unit

// Workspace layout (bytes) — total ~3.4 MB
#define WS_EFRAG 0                              // 2 MiB
#define WS_EN2   (2 * 1024 * 1024)              // 8192 f32: -0.5*||e||^2
#define WS_IDX   (WS_EN2 + K_EMB * 4)           // 32768 i32 (merged idx)
#define WS_KEY   (WS_IDX + N_ROWS * 4)          // 32768 u64 fixup keys
#define WS_BH    (WS_KEY + N_ROWS * 8)          // [2][N] best per K-half
#define WS_SH    (WS_BH + 2 * N_ROWS * 4)       // [2][N] second
#define WS_CH    (WS_SH + 2 * N_ROWS * 4)       // [2][N] idx
#define WS_CTL   (WS_CH + 2 * N_ROWS * 4)       // {double loss; int wl_count}
#define WS_WL    (WS_CTL + 16)                  // worklist

// Output layout (float32 elements): [quantized | loss | indices]
#define OUT_LOSS (N_ROWS * DIMS)
#define OUT_IDX  (N_ROWS * DIMS + 1)

__device__ inline short bfh(float v) {
    __hip_bfloat16 h = __float2bfloat16(v);
    return __builtin_bit_cast(short, h);
}
__device__ inline float bff(short s) {
    __hip_bfloat16 h = __builtin_bit_cast(__hip_bfloat16, s);
    return __bfloat162float(h);
}

// ---------------------------------------------------------------------------
// Prep: embeddings -> MFMA B-frag layout (hi/lo bf16 split) + fused -||e||^2/2.
// B-frag: lane holds B[k=(lane>>4)*8+j][n=lane&15]. Frags: 0=hi k[0,32),
// 1=hi k[32,64), 2=lo k[0,32), 3=lo k[32,64). [tile][frag][lane][16B].
// ---------------------------------------------------------------------------
__global__ void vq_prep(const float* __restrict__ emb, short* __restrict__ efrag,
                        float* __restrict__ en2) {
    int gid = blockIdx.x * 256 + threadIdx.x;   // NT*64 = 32768 threads
    int t = gid >> 6, lane = gid & 63;
    int m = lane & 15, q = lane >> 4;
    const float* er = emb + (size_t)(t * 16 + m) * DIMS;
    s8v hi0, lo0, hi1, lo1;
    float ss = 0.f;
#pragma unroll
    for (int j = 0; j < 8; ++j) {
        float v0 = er[q * 8 + j];
        float v1 = er[32 + q * 8 + j];
        ss += v0 * v0 + v1 * v1;
        short h0 = bfh(v0); lo0[j] = bfh(v0 - bff(h0)); hi0[j] = h0;
        short h1 = bfh(v1); lo1[j] = bfh(v1 - bff(h1)); hi1[j] = h1;
    }
    s8v* base = (s8v*)efrag + (size_t)t * 4 * 64;
    base[0 * 64 + lane] = hi0;
    base[1 * 64 + lane] = hi1;
    base[2 * 64 + lane] = lo0;
    base[3 * 64 + lane] = lo1;
    // reduce sum of squares across the 4 q-lanes sharing m
    ss += __shfl_xor(ss, 16, 64);
    ss += __shfl_xor(ss, 32, 64);
    if (q == 0) en2[t * 16 + m] = -0.5f * ss;
}

// ---------------------------------------------------------------------------
// Phase 1: LDS-staged split-bf16 MFMA distance + per-K-half argmax/second.
// Grid (256, 2): blockIdx.x = row-block (128 rows), blockIdx.y = K-half.
// 4 waves x 32 rows share each staged B tile; 8-tile double-buffered stages.
// ---------------------------------------------------------------------------
__global__ __launch_bounds__(256, 2) void vq_phase1(
    const float* __restrict__ x, const short* __restrict__ efrag,
    const float* __restrict__ en2,
    float* __restrict__ bh, float* __restrict__ sh, int* __restrict__ ch) {
    __shared__ __align__(16) char lds[2][TSTAGE * 4096];   // 64 KB
    int tid = threadIdx.x, wid = tid >> 6, lane = tid & 63;
    int m = lane & 15, q = lane >> 4;
    int kh = blockIdx.y;
    int row0 = blockIdx.x * 128 + wid * 32;

    // A-frags for 2 row-groups: A[m][k=quad*8+j], hi/lo, two K-halves of dims.
    s8v ahi[2][2], alo[2][2];
#pragma unroll
    for (int g = 0; g < 2; ++g) {
        const float* xr = x + (size_t)(row0 + g * 16 + m) * DIMS + q * 8;
#pragma unroll
        for (int j = 0; j < 8; ++j) {
            float v0 = xr[j], v1 = xr[32 + j];
            short h0 = bfh(v0); alo[g][0][j] = bfh(v0 - bff(h0)); ahi[g][0][j] = h0;
            short h1 = bfh(v1); alo[g][1][j] = bfh(v1 - bff(h1)); ahi[g][1][j] = h1;
        }
    }

    float best[2][4], sec[2][4];
    int bc[2][4];
#pragma unroll
    for (int g = 0; g < 2; ++g)
#pragma unroll
        for (int r = 0; r < 4; ++r) { best[g][r] = -FLT_MAX; sec[g][r] = -FLT_MAX; bc[g][r] = 0; }

    const char* gsrc = (const char*)efrag + (size_t)kh * NTH * 4096;

    // preload stage 0
#pragma unroll
    for (int i = 0; i < 8; ++i)
        __builtin_amdgcn_global_load_lds(
            (const __attribute__((address_space(1))) void*)(gsrc + i * 4096 + tid * 16),
            (__attribute__((address_space(3))) void*)(&lds[0][i * 4096 + tid * 16]),
            16, 0, 0);
    __syncthreads();

    for (int s = 0; s < NSTAGE; ++s) {
        int pb = s & 1;
        if (s + 1 < NSTAGE) {
            const char* gn = gsrc + (size_t)(s + 1) * TSTAGE * 4096;
#pragma unroll
            for (int i = 0; i < 8; ++i)
                __builtin_amdgcn_global_load_lds(
                    (const __attribute__((address_space(1))) void*)(gn + i * 4096 + tid * 16),
                    (__attribute__((address_space(3))) void*)(&lds[pb ^ 1][i * 4096 + tid * 16]),
                    16, 0, 0);
        }
        const i4v* B = (const i4v*)(lds[pb]);
        int tg0 = kh * NTH + s * TSTAGE;
        const float* ep = en2 + (size_t)tg0 * 16 + m;
#pragma unroll
        for (int tt = 0; tt < TSTAGE; ++tt) {
            i4v b0 = B[tt * 256 + 0 * 64 + lane];
            i4v b1 = B[tt * 256 + 1 * 64 + lane];
            i4v b2 = B[tt * 256 + 2 * 64 + lane];
            i4v b3 = B[tt * 256 + 3 * 64 + lane];
            float c0 = ep[tt * 16];
            int cidx = (tg0 + tt) * 16 + m;
#pragma unroll
            for (int g = 0; g < 2; ++g) {
                f4v acc = {c0, c0, c0, c0};   // C init = -||e_col||^2 / 2
                acc = __builtin_amdgcn_mfma_f32_16x16x32_bf16(ahi[g][0], __builtin_bit_cast(s8v, b0), acc, 0, 0, 0);
                acc = __builtin_amdgcn_mfma_f32_16x16x32_bf16(ahi[g][1], __builtin_bit_cast(s8v, b1), acc, 0, 0, 0);
                acc = __builtin_amdgcn_mfma_f32_16x16x32_bf16(ahi[g][0], __builtin_bit_cast(s8v, b2), acc, 0, 0, 0);
                acc = __builtin_amdgcn_mfma_f32_16x16x32_bf16(ahi[g][1], __builtin_bit_cast(s8v, b3), acc, 0, 0, 0);
                acc = __builtin_amdgcn_mfma_f32_16x16x32_bf16(alo[g][0], __builtin_bit_cast(s8v, b0), acc, 0, 0, 0);
                acc = __builtin_amdgcn_mfma_f32_16x16x32_bf16(alo[g][1], __builtin_bit_cast(s8v, b1), acc, 0, 0, 0);
#pragma unroll
                for (int r = 0; r < 4; ++r) {   // C/D: col=lane&15, row=quad*4+r
                    float v = acc[r];
                    bool gt = v > best[g][r];
                    sec[g][r]  = fmaxf(sec[g][r], fminf(v, best[g][r]));
                    best[g][r] = fmaxf(best[g][r], v);
                    bc[g][r]   = gt ? cidx : bc[g][r];
                }
            }
        }
        __syncthreads();
    }

    // Reduce (best, idx, second) across the 16 col-lanes of each quad.
#pragma unroll
    for (int g = 0; g < 2; ++g)
#pragma unroll
    for (int r = 0; r < 4; ++r) {
        float b = best[g][r], s = sec[g][r];
        int c = bc[g][r];
#pragma unroll
        for (int off = 1; off < 16; off <<= 1) {
            float ob = __shfl_xor(b, off, 64);
            float os = __shfl_xor(s, off, 64);
            int   oc = __shfl_xor(c, off, 64);
            float nb = fmaxf(b, ob);
            float ns = fmaxf(fminf(b, ob), fmaxf(s, os));
            bool take = (ob > b) || (ob == b && oc < c);  // tie -> lowest index
            c = take ? oc : c;
            b = nb; s = ns;
        }
        if (m == 0) {
            int o = kh * N_ROWS + row0 + g * 16 + q * 4 + r;
            bh[o] = b; sh[o] = s; ch[o] = c;
        }
    }
}

// ---------------------------------------------------------------------------
// Merge the two K-halves per row; zero fixup keys; build worklist.
// ---------------------------------------------------------------------------
__global__ void vq_merge(const float* __restrict__ bh, const float* __restrict__ sh,
                         const int* __restrict__ ch, int* __restrict__ idx_buf,
                         unsigned long long* __restrict__ key8,
                         int* __restrict__ wl, int* __restrict__ wl_count) {
    int row = blockIdx.x * 256 + threadIdx.x;
    float b0 = bh[row], b1 = bh[N_ROWS + row];
    float s0 = sh[row], s1 = sh[N_ROWS + row];
    int   c0 = ch[row], c1 = ch[N_ROWS + row];
    float nb = fmaxf(b0, b1);
    float ns = fmaxf(fminf(b0, b1), fmaxf(s0, s1));
    int c = (b1 > b0) ? c1 : c0;   // tie -> half 0 (lower cols)
    idx_buf[row] = c;
    key8[row] = 0ULL;
    if (nb - ns < GAP_THR) {
        int pos = atomicAdd(wl_count, 1);
        wl[pos] = row;
    }
}

// ---------------------------------------------------------------------------
// Fixup: exact fp32 rescan, 8 col-chunk blocks per flagged row, merged via
// atomicMax on packed (sortable(f) << 32 | ~idx) — exact argmax, ties->low idx.
// ---------------------------------------------------------------------------
__global__ __launch_bounds__(256) void vq_fixup(
    const float* __restrict__ x, const float* __restrict__ emb,
    const float* __restrict__ en2, unsigned long long* __restrict__ key8,
    const int* __restrict__ wl, const int* __restrict__ wl_count) {
    __shared__ float4 sx[16];
    __shared__ float sbf[4];
    __shared__ int   sbc[4];
    int tid = threadIdx.x, wid = tid >> 6, lane = tid & 63;
    int cnt = *wl_count;
    for (int wi = blockIdx.x; wi < cnt * 8; wi += gridDim.x) {
        int row = wl[wi >> 3];
        int cbase = (wi & 7) * (K_EMB / 8);
        if (tid < 16) sx[tid] = ((const float4*)(x + (size_t)row * DIMS))[tid];
        __syncthreads();
        float bf_ = -FLT_MAX;
        int bc_ = 0;
        for (int c = cbase + tid; c < cbase + K_EMB / 8; c += 256) {
            const float4* er = (const float4*)(emb + (size_t)c * DIMS);
            float d = 0.f;
#pragma unroll
            for (int qq = 0; qq < 16; ++qq) {
                float4 e = er[qq];
                float4 xx = sx[qq];
                d += e.x * xx.x + e.y * xx.y + e.z * xx.z + e.w * xx.w;
            }
            float f = d + en2[c];
            if (f > bf_) { bf_ = f; bc_ = c; }   // ascending c -> first occurrence
        }
#pragma unroll
        for (int off = 1; off < 64; off <<= 1) {
            float of = __shfl_xor(bf_, off, 64);
            int   oc = __shfl_xor(bc_, off, 64);
            if (of > bf_ || (of == bf_ && oc < bc_)) { bf_ = of; bc_ = oc; }
        }
        if (lane == 0) { sbf[wid] = bf_; sbc[wid] = bc_; }
        __syncthreads();
        if (tid == 0) {
            float b = sbf[0]; int c = sbc[0];
#pragma unroll
            for (int i = 1; i < 4; ++i)
                if (sbf[i] > b || (sbf[i] == b && sbc[i] < c)) { b = sbf[i]; c = sbc[i]; }
            unsigned int u = __float_as_uint(b);
            unsigned int sb = ((int)u < 0) ? ~u : (u | 0x80000000u);
            unsigned long long key = ((unsigned long long)sb << 32) | (unsigned int)(~c);
            atomicMax(&key8[row], key);
        }
        __syncthreads();
    }
}

// ---------------------------------------------------------------------------
// Gather quantized rows, accumulate squared error, emit indices as floats.
// ---------------------------------------------------------------------------
__global__ void vq_gather(const float* __restrict__ x, const float* __restrict__ emb,
                          const int* __restrict__ idx_buf,
                          const unsigned long long* __restrict__ key8,
                          float* __restrict__ out, double* __restrict__ loss_acc) {
    int row = blockIdx.x * blockDim.x + threadIdx.x;
    unsigned long long k = key8[row];
    int idx = k ? (int)(~(unsigned int)k) : idx_buf[row];
    const float4* ev = (const float4*)(emb + (size_t)idx * DIMS);
    const float4* xv = (const float4*)(x + (size_t)row * DIMS);
    float4* ov = (float4*)(out + (size_t)row * DIMS);
    float s = 0.f;
#pragma unroll
    for (int qq = 0; qq < 16; ++qq) {
        float4 ee = ev[qq];
        float4 xx = xv[qq];
        float dx = ee.x - xx.x, dy = ee.y - xx.y, dz = ee.z - xx.z, dw = ee.w - xx.w;
        s += dx * dx + dy * dy + dz * dz + dw * dw;
        ov[qq] = ee;
    }
#pragma unroll
    for (int off = 32; off > 0; off >>= 1) s += __shfl_down(s, off, 64);
    if ((threadIdx.x & 63) == 0) atomicAdd(loss_acc, (double)s);
    out[OUT_IDX + row] = (float)idx;
}

__global__ void vq_loss(const double* __restrict__ acc, float* __restrict__ out) {
    out[OUT_LOSS] = (float)(1.25 * (*acc) / (double)(N_ROWS * DIMS));
}

// ---------------------------------------------------------------------------
extern "C" void kernel_launch(void* const* d_in, const int* in_sizes, int n_in,
                              void* d_out, int out_size, void* d_ws, size_t ws_size,
                              hipStream_t stream) {
    const float* x   = (const float*)d_in[0];
    const float* emb = (const float*)d_in[1];
    float* out = (float*)d_out;
    char*  ws  = (char*)d_ws;

    short* efrag   = (short*)(ws + WS_EFRAG);
    float* en2     = (float*)(ws + WS_EN2);
    int*   idx_buf = (int*)(ws + WS_IDX);
    unsigned long long* key8 = (unsigned long long*)(ws + WS_KEY);
    float* bhb     = (float*)(ws + WS_BH);
    float* shb     = (float*)(ws + WS_SH);
    int*   chb     = (int*)(ws + WS_CH);
    double* loss_acc = (double*)(ws + WS_CTL);
    int*   wl_count  = (int*)(ws + WS_CTL + 8);
    int*   wl        = (int*)(ws + WS_WL);

    hipMemsetAsync(ws + WS_CTL, 0, 16, stream);   // loss + wl_count

    vq_prep<<<(NT * 64) / 256, 256, 0, stream>>>(emb, efrag, en2);       // 128 blocks
    vq_phase1<<<dim3(N_ROWS / 128, 2), 256, 0, stream>>>(x, efrag, en2, bhb, shb, chb);  // 512 blocks
    vq_merge<<<N_ROWS / 256, 256, 0, stream>>>(bhb, shb, chb, idx_buf, key8, wl, wl_count);
    vq_fixup<<<2048, 256, 0, stream>>>(x, emb, en2, key8, wl, wl_count);
    vq_gather<<<N_ROWS / 256, 256, 0, stream>>>(x, emb, idx_buf, key8, out, loss_acc);
    vq_loss<<<1, 1, 0, stream>>>(loss_acc, out);
}